// Round 7
// baseline (1402.392 us; speedup 1.0000x reference)
//
#include <hip/hip_runtime.h>

#define T_STEPS 1000
#define BATCH   64
#define FIN     128
#define HID     512
#define NOUT    32
#define ALPHA_F 0.2231435511314f
#define PFD     4          // scan steps per block == prefetch distance
#define WREC_ROWS (HID + 8)   // 8 zero rows for branchless padded gather

// ---------------- prep: weight transposes (+ zero pad rows) ----------------
__global__ void prep_transpose(const float* __restrict__ w_rec,
                               const float* __restrict__ w_out,
                               float* __restrict__ wrecT,
                               float* __restrict__ woutT) {
    int idx = blockIdx.x * blockDim.x + threadIdx.x;
    if (idx < HID * HID) {
        int j = idx / HID, h = idx % HID;
        wrecT[h * HID + j] = w_rec[idx];          // wrecT[h][j] = w_rec[j][h]
    } else if (idx < HID * HID + 8 * HID) {
        wrecT[idx] = 0.0f;                        // rows 512..519 = zeros
    }
    if (idx < NOUT * HID) {
        int o = idx / HID, h = idx % HID;
        woutT[h * NOUT + o] = w_out[idx];         // woutT[h][o] = w_out[o][h]
    }
}

// ---------------- prep: XWin[tb][h] = sum_k x[tb][k] * w_in[h][k] ----------------
#define GTM 128
#define GTN 128
#define GKC 32

__global__ __launch_bounds__(256)
void xwin_gemm(const float* __restrict__ x, const float* __restrict__ w_in,
               float* __restrict__ xwin) {
    __shared__ float xs[GKC][GTM + 4];
    __shared__ float ws[GKC][GTN + 4];
    const int tid = threadIdx.x;
    const int tb_base = blockIdx.x * GTM;
    const int h_base  = blockIdx.y * GTN;
    const int tx = tid & 15, ty = tid >> 4;

    float acc[8][8];
#pragma unroll
    for (int i = 0; i < 8; ++i)
#pragma unroll
        for (int j = 0; j < 8; ++j) acc[i][j] = 0.f;

    for (int kc = 0; kc < FIN; kc += GKC) {
#pragma unroll
        for (int q = 0; q < 4; ++q) {
            int li  = tid * 4 + q;
            int row = li >> 3, c4 = li & 7;
            float4 v = *(const float4*)&x[(size_t)(tb_base + row) * FIN + kc + c4 * 4];
            xs[c4*4+0][row] = v.x; xs[c4*4+1][row] = v.y;
            xs[c4*4+2][row] = v.z; xs[c4*4+3][row] = v.w;
            float4 w = *(const float4*)&w_in[(size_t)(h_base + row) * FIN + kc + c4 * 4];
            ws[c4*4+0][row] = w.x; ws[c4*4+1][row] = w.y;
            ws[c4*4+2][row] = w.z; ws[c4*4+3][row] = w.w;
        }
        __syncthreads();
#pragma unroll
        for (int k = 0; k < GKC; ++k) {
            float4 a0 = *(const float4*)&xs[k][tx * 8];
            float4 a1 = *(const float4*)&xs[k][tx * 8 + 4];
            float4 b0 = *(const float4*)&ws[k][ty * 8];
            float4 b1 = *(const float4*)&ws[k][ty * 8 + 4];
            float av[8] = {a0.x, a0.y, a0.z, a0.w, a1.x, a1.y, a1.z, a1.w};
            float bv[8] = {b0.x, b0.y, b0.z, b0.w, b1.x, b1.y, b1.z, b1.w};
#pragma unroll
            for (int i = 0; i < 8; ++i)
#pragma unroll
                for (int j = 0; j < 8; ++j)
                    acc[i][j] = fmaf(av[i], bv[j], acc[i][j]);
        }
        __syncthreads();
    }
#pragma unroll
    for (int i = 0; i < 8; ++i) {
        size_t tb = (size_t)tb_base + tx * 8 + i;
        float4 o0 = make_float4(acc[i][0], acc[i][1], acc[i][2], acc[i][3]);
        float4 o1 = make_float4(acc[i][4], acc[i][5], acc[i][6], acc[i][7]);
        *(float4*)&xwin[tb * HID + h_base + ty * 8]     = o0;
        *(float4*)&xwin[tb * HID + h_base + ty * 8 + 4] = o1;
    }
}

__device__ __forceinline__ float4 f4add(float4 a, float4 b) {
    return make_float4(a.x + b.x, a.y + b.y, a.z + b.z, a.w + b.w);
}

// ---------------- main scan: ONE WAVE per batch element, 8 neurons/lane ----------------
// neuron h = lane*8 + j; mask word j bit l <-> h = l*8 + j. Wave-uniform masks ->
// scalar decode. Gather: branchless fixed 16-slot budget (2/word), empty slots
// decode to zero rows 512..519 of wrT; ALL 32 loads in flight at once.
// __launch_bounds__(64,1): 1 wave/EU -> full 512-VGPR budget so the 32 float4
// results (128 VGPRs) stay resident; without this the compiler chunks the
// burst into serial load-wait groups (R5 regression: VGPR=128, 1163us).
__global__ __launch_bounds__(64, 1)
void snn_scan1w(const float* __restrict__ xwin,              // [T][B][H]
                const float* __restrict__ wrT,               // [WREC_ROWS][H]
                unsigned long long* __restrict__ masks) {    // [T][B][8]
    const int b    = blockIdx.x;
    const int lane = threadIdx.x;
    const size_t hoff = (size_t)lane * 8;

    float v[8], ic[8], rho[8];
    unsigned long long m[8];
#pragma unroll
    for (int j = 0; j < 8; ++j) { v[j] = 0.f; ic[j] = 0.f; rho[j] = 0.f; m[j] = 0ull; }

    float4 qa[PFD], qb[PFD];
#pragma unroll
    for (int s = 0; s < PFD; ++s) {
        const float* xp = &xwin[((size_t)s * BATCH + b) * HID + hoff];
        qa[s] = *(const float4*)xp;
        qb[s] = *(const float4*)(xp + 4);
    }

    for (int t0 = 0; t0 < T_STEPS; t0 += PFD) {
        // prefetch next block's xwin rows (independent loads)
        float4 pa[PFD], pb[PFD];
#pragma unroll
        for (int s = 0; s < PFD; ++s) {
            int tn = t0 + PFD + s; if (tn >= T_STEPS) tn = T_STEPS - 1;
            const float* xp = &xwin[((size_t)tn * BATCH + b) * HID + hoff];
            pa[s] = *(const float4*)xp;
            pb[s] = *(const float4*)(xp + 4);
        }

#pragma unroll
        for (int s = 0; s < PFD; ++s) {
            const int t = t0 + s;

            // ---- phase A: scalar decode into 16 padded slots ----
            unsigned long long mm[8];
            int hidx[16];
#pragma unroll
            for (int j = 0; j < 8; ++j) {
                unsigned long long w = m[j];
                int l0 = (w != 0ull) ? (int)__builtin_ctzll(w) : 64;
                w &= w - 1;
                int l1 = (w != 0ull) ? (int)__builtin_ctzll(w) : 64;
                w &= w - 1;
                hidx[2 * j]     = l0 * 8 + j;     // 512+j when empty -> zero row
                hidx[2 * j + 1] = l1 * 8 + j;
                mm[j] = w;                        // residue bits
            }

            // ---- phase B: issue all 32 loads back-to-back ----
            float4 wv0[16], wv1[16];
#pragma unroll
            for (int k = 0; k < 16; ++k) {
                const float* wp = &wrT[(size_t)hidx[k] * HID + hoff];
                wv0[k] = *(const float4*)wp;
                wv1[k] = *(const float4*)(wp + 4);
            }

            // ---- phase C: tree accumulate (4 independent chains of 4) ----
            float4 a0 = f4add(f4add(wv0[0], wv0[1]), f4add(wv0[2], wv0[3]));
            float4 a1 = f4add(f4add(wv0[4], wv0[5]), f4add(wv0[6], wv0[7]));
            float4 a2 = f4add(f4add(wv0[8], wv0[9]), f4add(wv0[10], wv0[11]));
            float4 a3 = f4add(f4add(wv0[12], wv0[13]), f4add(wv0[14], wv0[15]));
            float4 rl = f4add(f4add(a0, a1), f4add(a2, a3));
            float4 b0 = f4add(f4add(wv1[0], wv1[1]), f4add(wv1[2], wv1[3]));
            float4 b1 = f4add(f4add(wv1[4], wv1[5]), f4add(wv1[6], wv1[7]));
            float4 b2 = f4add(f4add(wv1[8], wv1[9]), f4add(wv1[10], wv1[11]));
            float4 b3 = f4add(f4add(wv1[12], wv1[13]), f4add(wv1[14], wv1[15]));
            float4 rh = f4add(f4add(b0, b1), f4add(b2, b3));
            float r[8] = {rl.x, rl.y, rl.z, rl.w, rh.x, rh.y, rh.z, rh.w};

            // ---- residue: >2 spikes in a word (rare), serial ----
#pragma unroll
            for (int j = 0; j < 8; ++j) {
                while (mm[j]) {
                    int l = (int)__builtin_ctzll(mm[j]);
                    mm[j] &= mm[j] - 1;
                    const float* wp = &wrT[(size_t)(l * 8 + j) * HID + hoff];
                    float4 wa = *(const float4*)wp;
                    float4 wb = *(const float4*)(wp + 4);
                    r[0] += wa.x; r[1] += wa.y; r[2] += wa.z; r[3] += wa.w;
                    r[4] += wb.x; r[5] += wb.y; r[6] += wb.z; r[7] += wb.w;
                }
            }

            // ---- LIF + refractory ----
            const float xi[8] = {qa[s].x, qa[s].y, qa[s].z, qa[s].w,
                                 qb[s].x, qb[s].y, qb[s].z, qb[s].w};
            float z[8];
#pragma unroll
            for (int j = 0; j < 8; ++j) {
                const float v_dec = v[j] + 0.1f * ((0.0f - v[j]) + ic[j]);
                const float i_dec = ic[j] * 0.8f;
                float zz     = (v_dec - 1.0f) > 0.0f ? 1.0f : 0.0f;
                float v_tmp  = (zz != 0.0f) ? 0.0f : v_dec;
                const float refr = (rho[j] > 0.0f) ? 1.0f : 0.0f;
                v[j]   = (refr != 0.0f) ? v[j] : v_tmp;
                zz     = (refr != 0.0f) ? 0.0f : zz;
                rho[j] = (zz != 0.0f) ? 5.0f : fmaxf(rho[j] - refr, 0.0f);
                ic[j]  = (i_dec + xi[j]) + r[j];
                z[j]   = zz;
            }
#pragma unroll
            for (int j = 0; j < 8; ++j) m[j] = __ballot(z[j] != 0.0f);

            if (lane == 0) {
                ulonglong2* mg = (ulonglong2*)&masks[((size_t)t * BATCH + b) * 8];
                ulonglong2 u0; u0.x = m[0]; u0.y = m[1];
                ulonglong2 u1; u1.x = m[2]; u1.y = m[3];
                ulonglong2 u2; u2.x = m[4]; u2.y = m[5];
                ulonglong2 u3; u3.x = m[6]; u3.y = m[7];
                mg[0] = u0; mg[1] = u1; mg[2] = u2; mg[3] = u3;
            }
        }
#pragma unroll
        for (int s = 0; s < PFD; ++s) { qa[s] = pa[s]; qb[s] = pb[s]; }
    }
}

// ---------------- readout pass 1: lin[t][b][o] = sum_spikes woutT[h][o] ----------------
__global__ __launch_bounds__(256)
void readout_lin(const unsigned long long* __restrict__ masks, // [T][B][8]
                 const float* __restrict__ woutT,              // [H][O]
                 float* __restrict__ lin) {                    // [T][B][O]
    __shared__ float s_w[HID * NOUT];
    const int tid = threadIdx.x;
#pragma unroll
    for (int q = 0; q < 16; ++q) {
        int fi = (q * 256 + tid) * 4;           // float index into [H][O]
        int h = fi >> 5, o = fi & 31;           // o is 4-aligned
        float4 w = *(const float4*)&woutT[fi];
        int xs = (h & 7) << 2;
        *(float4*)&s_w[(h << 5) + (o ^ xs)] = w;
    }
    __syncthreads();

    const int b  = blockIdx.y;
    const int t  = blockIdx.x * 64 + (tid & 63);
    const int o0 = (tid >> 6) * 8;
    if (t >= T_STEPS) return;

    const unsigned long long* mp = &masks[((size_t)t * BATCH + b) * 8];
    float a0 = 0.f, a1 = 0.f, a2 = 0.f, a3 = 0.f, a4 = 0.f, a5 = 0.f, a6 = 0.f, a7 = 0.f;
#pragma unroll
    for (int j = 0; j < 8; ++j) {
        unsigned long long mm = mp[j];
        while (mm) {
            int l = (int)__builtin_ctzll(mm);
            mm &= mm - 1;
            int h  = l * 8 + j;                 // matches scan kernel's mapping
            int xs = (h & 7) << 2;
            const float4 w0 = *(const float4*)&s_w[(h << 5) + (o0 ^ xs)];
            const float4 w1 = *(const float4*)&s_w[(h << 5) + ((o0 + 4) ^ xs)];
            a0 += w0.x; a1 += w0.y; a2 += w0.z; a3 += w0.w;
            a4 += w1.x; a5 += w1.y; a6 += w1.z; a7 += w1.w;
        }
    }
    float* op = &lin[((size_t)t * BATCH + b) * NOUT + o0];
    *(float4*)op       = make_float4(a0, a1, a2, a3);
    *(float4*)(op + 4) = make_float4(a4, a5, a6, a7);
}

// ---------------- readout pass 2: IIR filter, chunk-parallel with warmup ----------------
__global__ __launch_bounds__(256)
void readout_filter(const float* __restrict__ lin,   // [T][B*O]
                    const float* __restrict__ b_out,
                    float* __restrict__ out) {       // [T][B*O]
    const int bo = blockIdx.x * 256 + threadIdx.x;   // 0..2047
    const int c  = blockIdx.y;                       // chunk 0..7
    const float bb = b_out[bo & 31];
    const int t0 = c * 125;
    int ts = t0 - 128; if (ts < 0) ts = 0;
    const int te = t0 + 125;
    float o = 0.f;
    for (int t = ts; t < te; ++t) {
        float l = lin[(size_t)t * (BATCH * NOUT) + bo] + bb;
        o = o + ALPHA_F * (l - o);
        if (t >= t0) out[(size_t)t * (BATCH * NOUT) + bo] = o;
    }
}

// ---------------- legacy fallback (small-ws paths) ----------------
template<int PRECOMP>
__global__ __launch_bounds__(512)
void snn_main(const float* __restrict__ xsrc,
              const float* __restrict__ w_in,
              const float* __restrict__ wr, int wrA, int wrB,
              const float* __restrict__ wo, int woA, int woB,
              const float* __restrict__ b_out,
              float* __restrict__ out) {
    const int b    = blockIdx.x;
    const int tid  = threadIdx.x;
    const int lane = tid & 63;

    __shared__ int   s_list[2][HID];
    __shared__ int   s_cnt[2];
    __shared__ float s_xrow[2][FIN];

    if (tid < 2) s_cnt[tid] = 0;
    if (!PRECOMP && tid < FIN)
        s_xrow[0][tid] = xsrc[(size_t)b * FIN + tid];
    float iin_reg = 0.f;
    if (PRECOMP) iin_reg = xsrc[(size_t)b * HID + tid];
    __syncthreads();

    float v = 0.f, ic = 0.f, rho = 0.f, o_state = 0.f;
    const float bout_v = (tid < NOUT) ? b_out[tid] : 0.f;

    for (int t = 0; t < T_STEPS; ++t) {
        const int cur = t & 1, nxt = cur ^ 1;
        float iin_next = 0.f;
        if (PRECOMP) {
            int tn = (t + 1 < T_STEPS) ? (t + 1) : t;
            iin_next = xsrc[((size_t)tn * BATCH + b) * HID + tid];
        }
        float iin;
        if (PRECOMP) {
            iin = iin_reg;
        } else {
            float s0 = 0.f, s1 = 0.f, s2 = 0.f, s3 = 0.f;
#pragma unroll
            for (int kq = 0; kq < FIN / 4; ++kq) {
                float4 xv = *(const float4*)&s_xrow[cur][kq * 4];
                float4 wv = *(const float4*)&w_in[(size_t)tid * FIN + kq * 4];
                s0 = fmaf(xv.x, wv.x, s0); s1 = fmaf(xv.y, wv.y, s1);
                s2 = fmaf(xv.z, wv.z, s2); s3 = fmaf(xv.w, wv.w, s3);
            }
            iin = (s0 + s1) + (s2 + s3);
        }
        const int cn = s_cnt[cur];
        float r0 = 0.f, r1 = 0.f, r2 = 0.f, r3 = 0.f;
        int k = 0;
        for (; k + 4 <= cn; k += 4) {
            int i0 = s_list[cur][k],     i1 = s_list[cur][k + 1];
            int i2 = s_list[cur][k + 2], i3 = s_list[cur][k + 3];
            r0 += wr[(size_t)i0 * wrA + (size_t)tid * wrB];
            r1 += wr[(size_t)i1 * wrA + (size_t)tid * wrB];
            r2 += wr[(size_t)i2 * wrA + (size_t)tid * wrB];
            r3 += wr[(size_t)i3 * wrA + (size_t)tid * wrB];
        }
        for (; k < cn; ++k)
            r0 += wr[(size_t)s_list[cur][k] * wrA + (size_t)tid * wrB];
        const float rec = (r0 + r1) + (r2 + r3);

        const float v_dec = v + 0.1f * ((0.0f - v) + ic);
        const float i_dec = ic * 0.8f;
        float z      = (v_dec - 1.0f) > 0.0f ? 1.0f : 0.0f;
        float v_tmp  = (z != 0.0f) ? 0.0f : v_dec;
        const float refr = (rho > 0.0f) ? 1.0f : 0.0f;
        v   = (refr != 0.0f) ? v : v_tmp;
        z   = (refr != 0.0f) ? 0.0f : z;
        rho = (z != 0.0f) ? 5.0f : fmaxf(rho - refr, 0.0f);
        ic  = (i_dec + iin) + rec;

        unsigned long long mbal = __ballot(z != 0.0f);
        int nsp = __popcll(mbal);
        int base = 0;
        if (lane == 0 && nsp) base = atomicAdd(&s_cnt[nxt], nsp);
        base = __shfl(base, 0);
        if (z != 0.0f) {
            int pos = base + __popcll(mbal & ((1ull << lane) - 1ull));
            s_list[nxt][pos] = tid;
        }
        __syncthreads();

        if (tid < NOUT) {
            const int c2 = s_cnt[nxt];
            float lin = 0.f;
            for (int kk = 0; kk < c2; ++kk)
                lin += wo[(size_t)s_list[nxt][kk] * woA + (size_t)tid * woB];
            lin += bout_v;
            o_state = o_state + ALPHA_F * (lin - o_state);
            out[((size_t)t * BATCH + b) * NOUT + tid] = o_state;
        }
        if (tid == 0) s_cnt[cur] = 0;
        if (PRECOMP) iin_reg = iin_next;
        if (!PRECOMP && tid >= 128 && tid < 128 + FIN) {
            int tn = (t + 1 < T_STEPS) ? (t + 1) : t;
            s_xrow[nxt][tid - 128] = xsrc[((size_t)tn * BATCH + b) * HID + (tid - 128)];
        }
        __syncthreads();
    }
}

extern "C" void kernel_launch(void* const* d_in, const int* in_sizes, int n_in,
                              void* d_out, int out_size, void* d_ws, size_t ws_size,
                              hipStream_t stream) {
    const float* x     = (const float*)d_in[0];
    const float* w_in  = (const float*)d_in[1];
    const float* w_rec = (const float*)d_in[2];
    const float* w_out = (const float*)d_in[3];
    const float* b_out = (const float*)d_in[4];
    float* out = (float*)d_out;

    const size_t xwin_b  = (size_t)T_STEPS * BATCH * HID * sizeof(float);   // 131.072 MB
    const size_t masks_b = (size_t)T_STEPS * BATCH * 8 * sizeof(unsigned long long); // 4.096 MB
    const size_t wrect_b = (size_t)WREC_ROWS * HID * sizeof(float);         // 1.065 MB
    const size_t woutt_b = (size_t)HID * NOUT * sizeof(float);              // 64 KB

    char* ws = (char*)d_ws;
    const int prep_n = HID * HID + 8 * HID;

    if (ws_size >= xwin_b + masks_b + wrect_b + woutt_b) {
        float* xwin  = (float*)ws;                       // dead after scan
        float* lin   = (float*)ws;                       // overlays xwin
        unsigned long long* masks = (unsigned long long*)(ws + xwin_b);
        float* wrecT = (float*)(ws + xwin_b + masks_b);
        float* woutT = (float*)(ws + xwin_b + masks_b + wrect_b);

        prep_transpose<<<(prep_n + 255) / 256, 256, 0, stream>>>(w_rec, w_out, wrecT, woutT);
        dim3 g(T_STEPS * BATCH / GTM, HID / GTN);
        xwin_gemm<<<g, 256, 0, stream>>>(x, w_in, xwin);
        snn_scan1w<<<BATCH, 64, 0, stream>>>(xwin, wrecT, masks);
        readout_lin<<<dim3((T_STEPS + 63) / 64, BATCH), 256, 0, stream>>>(masks, woutT, lin);
        readout_filter<<<dim3(BATCH * NOUT / 256, 8), 256, 0, stream>>>(lin, b_out, out);
    } else if (ws_size >= xwin_b + wrect_b + woutt_b) {
        float* xwin  = (float*)ws;
        float* wrecT = (float*)(ws + xwin_b);
        float* woutT = (float*)(ws + xwin_b + wrect_b);
        prep_transpose<<<(prep_n + 255) / 256, 256, 0, stream>>>(w_rec, w_out, wrecT, woutT);
        dim3 g(T_STEPS * BATCH / GTM, HID / GTN);
        xwin_gemm<<<g, 256, 0, stream>>>(x, w_in, xwin);
        snn_main<1><<<BATCH, HID, 0, stream>>>(xwin, nullptr, wrecT, HID, 1,
                                               woutT, NOUT, 1, b_out, out);
    } else if (ws_size >= wrect_b + woutt_b) {
        float* wrecT = (float*)ws;
        float* woutT = (float*)(ws + wrect_b);
        prep_transpose<<<(prep_n + 255) / 256, 256, 0, stream>>>(w_rec, w_out, wrecT, woutT);
        snn_main<0><<<BATCH, HID, 0, stream>>>(x, w_in, wrecT, HID, 1,
                                               woutT, NOUT, 1, b_out, out);
    } else {
        snn_main<0><<<BATCH, HID, 0, stream>>>(x, w_in, w_rec, 1, HID,
                                               w_out, 1, HID, b_out, out);
    }
}

// Round 11
// 1252.841 us; speedup vs baseline: 1.1194x; 1.1194x over previous
//
#include <hip/hip_runtime.h>

#define T_STEPS 1000
#define BATCH   64
#define FIN     128
#define HID     512
#define NOUT    32
#define ALPHA_F 0.2231435511314f
#define PFD     4             // xwin prefetch distance (steps)
#define WREC_ROWS (HID + 8)   // row 512.. = zeros for branchless padded gather

// ---------------- prep: weight transposes (+ zero pad rows) ----------------
__global__ void prep_transpose(const float* __restrict__ w_rec,
                               const float* __restrict__ w_out,
                               float* __restrict__ wrecT,
                               float* __restrict__ woutT) {
    int idx = blockIdx.x * blockDim.x + threadIdx.x;
    if (idx < HID * HID) {
        int j = idx / HID, h = idx % HID;
        wrecT[h * HID + j] = w_rec[idx];          // wrecT[h][j] = w_rec[j][h]
    } else if (idx < HID * HID + 8 * HID) {
        wrecT[idx] = 0.0f;                        // rows 512..519 = zeros
    }
    if (idx < NOUT * HID) {
        int o = idx / HID, h = idx % HID;
        woutT[h * NOUT + o] = w_out[idx];         // woutT[h][o] = w_out[o][h]
    }
}

// ---------------- prep: XWin[tb][h] = sum_k x[tb][k] * w_in[h][k] ----------------
#define GTM 128
#define GTN 128
#define GKC 32

__global__ __launch_bounds__(256)
void xwin_gemm(const float* __restrict__ x, const float* __restrict__ w_in,
               float* __restrict__ xwin) {
    __shared__ float xs[GKC][GTM + 4];
    __shared__ float ws[GKC][GTN + 4];
    const int tid = threadIdx.x;
    const int tb_base = blockIdx.x * GTM;
    const int h_base  = blockIdx.y * GTN;
    const int tx = tid & 15, ty = tid >> 4;

    float acc[8][8];
#pragma unroll
    for (int i = 0; i < 8; ++i)
#pragma unroll
        for (int j = 0; j < 8; ++j) acc[i][j] = 0.f;

    for (int kc = 0; kc < FIN; kc += GKC) {
#pragma unroll
        for (int q = 0; q < 4; ++q) {
            int li  = tid * 4 + q;
            int row = li >> 3, c4 = li & 7;
            float4 v = *(const float4*)&x[(size_t)(tb_base + row) * FIN + kc + c4 * 4];
            xs[c4*4+0][row] = v.x; xs[c4*4+1][row] = v.y;
            xs[c4*4+2][row] = v.z; xs[c4*4+3][row] = v.w;
            float4 w = *(const float4*)&w_in[(size_t)(h_base + row) * FIN + kc + c4 * 4];
            ws[c4*4+0][row] = w.x; ws[c4*4+1][row] = w.y;
            ws[c4*4+2][row] = w.z; ws[c4*4+3][row] = w.w;
        }
        __syncthreads();
#pragma unroll
        for (int k = 0; k < GKC; ++k) {
            float4 a0 = *(const float4*)&xs[k][tx * 8];
            float4 a1 = *(const float4*)&xs[k][tx * 8 + 4];
            float4 b0 = *(const float4*)&ws[k][ty * 8];
            float4 b1 = *(const float4*)&ws[k][ty * 8 + 4];
            float av[8] = {a0.x, a0.y, a0.z, a0.w, a1.x, a1.y, a1.z, a1.w};
            float bv[8] = {b0.x, b0.y, b0.z, b0.w, b1.x, b1.y, b1.z, b1.w};
#pragma unroll
            for (int i = 0; i < 8; ++i)
#pragma unroll
                for (int j = 0; j < 8; ++j)
                    acc[i][j] = fmaf(av[i], bv[j], acc[i][j]);
        }
        __syncthreads();
    }
#pragma unroll
    for (int i = 0; i < 8; ++i) {
        size_t tb = (size_t)tb_base + tx * 8 + i;
        float4 o0 = make_float4(acc[i][0], acc[i][1], acc[i][2], acc[i][3]);
        float4 o1 = make_float4(acc[i][4], acc[i][5], acc[i][6], acc[i][7]);
        *(float4*)&xwin[tb * HID + h_base + ty * 8]     = o0;
        *(float4*)&xwin[tb * HID + h_base + ty * 8 + 4] = o1;
    }
}

// ---------------- main scan: FOUR waves per batch element, 2 neurons/thread ----
// Thread tid owns neurons h0=tid, h1=tid+256. Mask word j bit l <-> h=64j+l:
//   wave w's __ballot(z0) IS word w; __ballot(z1) IS word w+4 (no bit math).
// Words exchanged via 128B double-buffered LDS, ONE barrier/step.
// Gather: 16 padded slots (2/word; empty -> zero row 512); each thread loads
// its own 2 columns per slot -> 32 coalesced dword loads, 32 VGPRs of results
// (small enough that the compiler actually keeps the burst in flight — the
// 1-wave float4x32 variant was chunked into serial groups, R5/R7).
__global__ __launch_bounds__(256, 1)
void snn_scan4w(const float* __restrict__ xwin,              // [T][B][H]
                const float* __restrict__ wrT,               // [WREC_ROWS][H]
                unsigned long long* __restrict__ masks) {    // [T][B][8]
    const int b    = blockIdx.x;
    const int tid  = threadIdx.x;
    const int w    = tid >> 6;
    const int lane = tid & 63;
    const int h0 = tid, h1 = tid + 256;

    __shared__ __align__(16) unsigned long long smasks[2][8];
    if (tid < 16) ((unsigned long long*)smasks)[tid] = 0ull;
    __syncthreads();

    float v0 = 0.f, v1 = 0.f, c0 = 0.f, c1 = 0.f, q0 = 0.f, q1 = 0.f; // v, i, rho

    const float* wp0 = wrT + h0;   // column base pointers
    const float* wp1 = wrT + h1;

    float xq0[PFD], xq1[PFD];
#pragma unroll
    for (int s = 0; s < PFD; ++s) {
        xq0[s] = xwin[((size_t)s * BATCH + b) * HID + h0];
        xq1[s] = xwin[((size_t)s * BATCH + b) * HID + h1];
    }

    for (int t0 = 0; t0 < T_STEPS; t0 += PFD) {
        float pa0[PFD], pa1[PFD];
#pragma unroll
        for (int s = 0; s < PFD; ++s) {
            int tn = t0 + PFD + s; if (tn >= T_STEPS) tn = T_STEPS - 1;
            pa0[s] = xwin[((size_t)tn * BATCH + b) * HID + h0];
            pa1[s] = xwin[((size_t)tn * BATCH + b) * HID + h1];
        }

#pragma unroll
        for (int s = 0; s < PFD; ++s) {
            const int t = t0 + s;
            const int cur = t & 1, nxt = cur ^ 1;

            // ---- read previous-step masks (broadcast LDS read) ----
            const ulonglong2* sp = (const ulonglong2*)&smasks[cur][0];
            ulonglong2 u0 = sp[0], u1 = sp[1], u2 = sp[2], u3 = sp[3];
            unsigned long long wd[8] = {u0.x, u0.y, u1.x, u1.y,
                                        u2.x, u2.y, u3.x, u3.y};

            // ---- decode 16 padded slots (2 per word) ----
            int rows[16];
            unsigned long long rem[8];
#pragma unroll
            for (int j = 0; j < 8; ++j) {
                unsigned long long u = wd[j];
                int l0 = (u != 0ull) ? (int)__builtin_ctzll(u) : 64;
                u &= u - 1;
                int l1 = (u != 0ull) ? (int)__builtin_ctzll(u) : 64;
                u &= u - 1;
                rows[2 * j]     = (l0 < 64) ? (j * 64 + l0) : HID;  // HID = zero row
                rows[2 * j + 1] = (l1 < 64) ? (j * 64 + l1) : HID;
                rem[j] = u;
            }

            // ---- gather burst: 32 coalesced dword loads ----
            float g0[16], g1[16];
#pragma unroll
            for (int k = 0; k < 16; ++k) {
                const size_t off = (size_t)rows[k] * HID;
                g0[k] = wp0[off];
                g1[k] = wp1[off];
            }

            // ---- tree accumulate ----
            float rec0 = (((g0[0]+g0[1])+(g0[2]+g0[3])) + ((g0[4]+g0[5])+(g0[6]+g0[7])))
                       + (((g0[8]+g0[9])+(g0[10]+g0[11])) + ((g0[12]+g0[13])+(g0[14]+g0[15])));
            float rec1 = (((g1[0]+g1[1])+(g1[2]+g1[3])) + ((g1[4]+g1[5])+(g1[6]+g1[7])))
                       + (((g1[8]+g1[9])+(g1[10]+g1[11])) + ((g1[12]+g1[13])+(g1[14]+g1[15])));

            // ---- residue: >2 spikes in a word (rare, wave-uniform) ----
#pragma unroll
            for (int j = 0; j < 8; ++j) {
                while (rem[j]) {
                    int l = (int)__builtin_ctzll(rem[j]);
                    rem[j] &= rem[j] - 1;
                    const size_t off = (size_t)(j * 64 + l) * HID;
                    rec0 += wp0[off];
                    rec1 += wp1[off];
                }
            }

            // ---- LIF + refractory (both neurons) ----
            float z0, z1;
            {
                const float v_dec = v0 + 0.1f * ((0.0f - v0) + c0);
                const float i_dec = c0 * 0.8f;
                float zz = (v_dec - 1.0f) > 0.0f ? 1.0f : 0.0f;
                float v_tmp = (zz != 0.0f) ? 0.0f : v_dec;
                const float refr = (q0 > 0.0f) ? 1.0f : 0.0f;
                v0 = (refr != 0.0f) ? v0 : v_tmp;
                zz = (refr != 0.0f) ? 0.0f : zz;
                q0 = (zz != 0.0f) ? 5.0f : fmaxf(q0 - refr, 0.0f);
                c0 = (i_dec + xq0[s]) + rec0;
                z0 = zz;
            }
            {
                const float v_dec = v1 + 0.1f * ((0.0f - v1) + c1);
                const float i_dec = c1 * 0.8f;
                float zz = (v_dec - 1.0f) > 0.0f ? 1.0f : 0.0f;
                float v_tmp = (zz != 0.0f) ? 0.0f : v_dec;
                const float refr = (q1 > 0.0f) ? 1.0f : 0.0f;
                v1 = (refr != 0.0f) ? v1 : v_tmp;
                zz = (refr != 0.0f) ? 0.0f : zz;
                q1 = (zz != 0.0f) ? 5.0f : fmaxf(q1 - refr, 0.0f);
                c1 = (i_dec + xq1[s]) + rec1;
                z1 = zz;
            }

            const unsigned long long mA = __ballot(z0 != 0.0f);  // word w
            const unsigned long long mB = __ballot(z1 != 0.0f);  // word w+4

            if (lane == 0) {
                smasks[nxt][w]     = mA;
                smasks[nxt][4 + w] = mB;
                unsigned long long* mg = &masks[((size_t)t * BATCH + b) * 8];
                mg[w]     = mA;
                mg[4 + w] = mB;
            }
            __syncthreads();   // publish smasks[nxt]; also fences next overwrite
        }
#pragma unroll
        for (int s = 0; s < PFD; ++s) { xq0[s] = pa0[s]; xq1[s] = pa1[s]; }
    }
}

// ---------------- readout pass 1: lin[t][b][o] = sum_spikes woutT[h][o] ----------------
// mask mapping (scan4w): word j bit l <-> h = 64*j + l
__global__ __launch_bounds__(256)
void readout_lin(const unsigned long long* __restrict__ masks, // [T][B][8]
                 const float* __restrict__ woutT,              // [H][O]
                 float* __restrict__ lin) {                    // [T][B][O]
    __shared__ float s_w[HID * NOUT];
    const int tid = threadIdx.x;
#pragma unroll
    for (int q = 0; q < 16; ++q) {
        int fi = (q * 256 + tid) * 4;           // float index into [H][O]
        int h = fi >> 5, o = fi & 31;           // o is 4-aligned
        float4 w = *(const float4*)&woutT[fi];
        int xs = (h & 7) << 2;
        *(float4*)&s_w[(h << 5) + (o ^ xs)] = w;
    }
    __syncthreads();

    const int b  = blockIdx.y;
    const int t  = blockIdx.x * 64 + (tid & 63);
    const int o0 = (tid >> 6) * 8;
    if (t >= T_STEPS) return;

    const unsigned long long* mp = &masks[((size_t)t * BATCH + b) * 8];
    float a0 = 0.f, a1 = 0.f, a2 = 0.f, a3 = 0.f, a4 = 0.f, a5 = 0.f, a6 = 0.f, a7 = 0.f;
#pragma unroll
    for (int j = 0; j < 8; ++j) {
        unsigned long long mm = mp[j];
        while (mm) {
            int l = (int)__builtin_ctzll(mm);
            mm &= mm - 1;
            int h  = j * 64 + l;                // scan4w mapping
            int xs = (h & 7) << 2;
            const float4 w0 = *(const float4*)&s_w[(h << 5) + (o0 ^ xs)];
            const float4 w1 = *(const float4*)&s_w[(h << 5) + ((o0 + 4) ^ xs)];
            a0 += w0.x; a1 += w0.y; a2 += w0.z; a3 += w0.w;
            a4 += w1.x; a5 += w1.y; a6 += w1.z; a7 += w1.w;
        }
    }
    float* op = &lin[((size_t)t * BATCH + b) * NOUT + o0];
    *(float4*)op       = make_float4(a0, a1, a2, a3);
    *(float4*)(op + 4) = make_float4(a4, a5, a6, a7);
}

// ---------------- readout pass 2: IIR filter, chunk-parallel with warmup ----------------
__global__ __launch_bounds__(256)
void readout_filter(const float* __restrict__ lin,   // [T][B*O]
                    const float* __restrict__ b_out,
                    float* __restrict__ out) {       // [T][B*O]
    const int bo = blockIdx.x * 256 + threadIdx.x;   // 0..2047
    const int c  = blockIdx.y;                       // chunk 0..7
    const float bb = b_out[bo & 31];
    const int t0 = c * 125;
    int ts = t0 - 128; if (ts < 0) ts = 0;
    const int te = t0 + 125;
    float o = 0.f;
    for (int t = ts; t < te; ++t) {
        float l = lin[(size_t)t * (BATCH * NOUT) + bo] + bb;
        o = o + ALPHA_F * (l - o);
        if (t >= t0) out[(size_t)t * (BATCH * NOUT) + bo] = o;
    }
}

// ---------------- legacy fallback (small-ws paths) ----------------
template<int PRECOMP>
__global__ __launch_bounds__(512)
void snn_main(const float* __restrict__ xsrc,
              const float* __restrict__ w_in,
              const float* __restrict__ wr, int wrA, int wrB,
              const float* __restrict__ wo, int woA, int woB,
              const float* __restrict__ b_out,
              float* __restrict__ out) {
    const int b    = blockIdx.x;
    const int tid  = threadIdx.x;
    const int lane = tid & 63;

    __shared__ int   s_list[2][HID];
    __shared__ int   s_cnt[2];
    __shared__ float s_xrow[2][FIN];

    if (tid < 2) s_cnt[tid] = 0;
    if (!PRECOMP && tid < FIN)
        s_xrow[0][tid] = xsrc[(size_t)b * FIN + tid];
    float iin_reg = 0.f;
    if (PRECOMP) iin_reg = xsrc[(size_t)b * HID + tid];
    __syncthreads();

    float v = 0.f, ic = 0.f, rho = 0.f, o_state = 0.f;
    const float bout_v = (tid < NOUT) ? b_out[tid] : 0.f;

    for (int t = 0; t < T_STEPS; ++t) {
        const int cur = t & 1, nxt = cur ^ 1;
        float iin_next = 0.f;
        if (PRECOMP) {
            int tn = (t + 1 < T_STEPS) ? (t + 1) : t;
            iin_next = xsrc[((size_t)tn * BATCH + b) * HID + tid];
        }
        float iin;
        if (PRECOMP) {
            iin = iin_reg;
        } else {
            float s0 = 0.f, s1 = 0.f, s2 = 0.f, s3 = 0.f;
#pragma unroll
            for (int kq = 0; kq < FIN / 4; ++kq) {
                float4 xv = *(const float4*)&s_xrow[cur][kq * 4];
                float4 wv = *(const float4*)&w_in[(size_t)tid * FIN + kq * 4];
                s0 = fmaf(xv.x, wv.x, s0); s1 = fmaf(xv.y, wv.y, s1);
                s2 = fmaf(xv.z, wv.z, s2); s3 = fmaf(xv.w, wv.w, s3);
            }
            iin = (s0 + s1) + (s2 + s3);
        }
        const int cn = s_cnt[cur];
        float r0 = 0.f, r1 = 0.f, r2 = 0.f, r3 = 0.f;
        int k = 0;
        for (; k + 4 <= cn; k += 4) {
            int i0 = s_list[cur][k],     i1 = s_list[cur][k + 1];
            int i2 = s_list[cur][k + 2], i3 = s_list[cur][k + 3];
            r0 += wr[(size_t)i0 * wrA + (size_t)tid * wrB];
            r1 += wr[(size_t)i1 * wrA + (size_t)tid * wrB];
            r2 += wr[(size_t)i2 * wrA + (size_t)tid * wrB];
            r3 += wr[(size_t)i3 * wrA + (size_t)tid * wrB];
        }
        for (; k < cn; ++k)
            r0 += wr[(size_t)s_list[cur][k] * wrA + (size_t)tid * wrB];
        const float rec = (r0 + r1) + (r2 + r3);

        const float v_dec = v + 0.1f * ((0.0f - v) + ic);
        const float i_dec = ic * 0.8f;
        float z      = (v_dec - 1.0f) > 0.0f ? 1.0f : 0.0f;
        float v_tmp  = (z != 0.0f) ? 0.0f : v_dec;
        const float refr = (rho > 0.0f) ? 1.0f : 0.0f;
        v   = (refr != 0.0f) ? v : v_tmp;
        z   = (refr != 0.0f) ? 0.0f : z;
        rho = (z != 0.0f) ? 5.0f : fmaxf(rho - refr, 0.0f);
        ic  = (i_dec + iin) + rec;

        unsigned long long mbal = __ballot(z != 0.0f);
        int nsp = __popcll(mbal);
        int base = 0;
        if (lane == 0 && nsp) base = atomicAdd(&s_cnt[nxt], nsp);
        base = __shfl(base, 0);
        if (z != 0.0f) {
            int pos = base + __popcll(mbal & ((1ull << lane) - 1ull));
            s_list[nxt][pos] = tid;
        }
        __syncthreads();

        if (tid < NOUT) {
            const int c2 = s_cnt[nxt];
            float lin = 0.f;
            for (int kk = 0; kk < c2; ++kk)
                lin += wo[(size_t)s_list[nxt][kk] * woA + (size_t)tid * woB];
            lin += bout_v;
            o_state = o_state + ALPHA_F * (lin - o_state);
            out[((size_t)t * BATCH + b) * NOUT + tid] = o_state;
        }
        if (tid == 0) s_cnt[cur] = 0;
        if (PRECOMP) iin_reg = iin_next;
        if (!PRECOMP && tid >= 128 && tid < 128 + FIN) {
            int tn = (t + 1 < T_STEPS) ? (t + 1) : t;
            s_xrow[nxt][tid - 128] = xsrc[((size_t)tn * BATCH + b) * FIN + (tid - 128)];
        }
        __syncthreads();
    }
}

extern "C" void kernel_launch(void* const* d_in, const int* in_sizes, int n_in,
                              void* d_out, int out_size, void* d_ws, size_t ws_size,
                              hipStream_t stream) {
    const float* x     = (const float*)d_in[0];
    const float* w_in  = (const float*)d_in[1];
    const float* w_rec = (const float*)d_in[2];
    const float* w_out = (const float*)d_in[3];
    const float* b_out = (const float*)d_in[4];
    float* out = (float*)d_out;

    const size_t xwin_b  = (size_t)T_STEPS * BATCH * HID * sizeof(float);   // 131.072 MB
    const size_t masks_b = (size_t)T_STEPS * BATCH * 8 * sizeof(unsigned long long); // 4.096 MB
    const size_t wrect_b = (size_t)WREC_ROWS * HID * sizeof(float);         // 1.065 MB
    const size_t woutt_b = (size_t)HID * NOUT * sizeof(float);              // 64 KB

    char* ws = (char*)d_ws;
    const int prep_n = HID * HID + 8 * HID;

    if (ws_size >= xwin_b + masks_b + wrect_b + woutt_b) {
        float* xwin  = (float*)ws;                       // dead after scan
        float* lin   = (float*)ws;                       // overlays xwin
        unsigned long long* masks = (unsigned long long*)(ws + xwin_b);
        float* wrecT = (float*)(ws + xwin_b + masks_b);
        float* woutT = (float*)(ws + xwin_b + masks_b + wrect_b);

        prep_transpose<<<(prep_n + 255) / 256, 256, 0, stream>>>(w_rec, w_out, wrecT, woutT);
        dim3 g(T_STEPS * BATCH / GTM, HID / GTN);
        xwin_gemm<<<g, 256, 0, stream>>>(x, w_in, xwin);
        snn_scan4w<<<BATCH, 256, 0, stream>>>(xwin, wrecT, masks);
        readout_lin<<<dim3((T_STEPS + 63) / 64, BATCH), 256, 0, stream>>>(masks, woutT, lin);
        readout_filter<<<dim3(BATCH * NOUT / 256, 8), 256, 0, stream>>>(lin, b_out, out);
    } else if (ws_size >= xwin_b + wrect_b + woutt_b) {
        float* xwin  = (float*)ws;
        float* wrecT = (float*)(ws + xwin_b);
        float* woutT = (float*)(ws + xwin_b + wrect_b);
        prep_transpose<<<(prep_n + 255) / 256, 256, 0, stream>>>(w_rec, w_out, wrecT, woutT);
        dim3 g(T_STEPS * BATCH / GTM, HID / GTN);
        xwin_gemm<<<g, 256, 0, stream>>>(x, w_in, xwin);
        snn_main<1><<<BATCH, HID, 0, stream>>>(xwin, nullptr, wrecT, HID, 1,
                                               woutT, NOUT, 1, b_out, out);
    } else if (ws_size >= wrect_b + woutt_b) {
        float* wrecT = (float*)ws;
        float* woutT = (float*)(ws + wrect_b);
        prep_transpose<<<(prep_n + 255) / 256, 256, 0, stream>>>(w_rec, w_out, wrecT, woutT);
        snn_main<0><<<BATCH, HID, 0, stream>>>(x, w_in, wrecT, HID, 1,
                                               woutT, NOUT, 1, b_out, out);
    } else {
        snn_main<0><<<BATCH, HID, 0, stream>>>(x, w_in, w_rec, 1, HID,
                                               w_out, 1, HID, b_out, out);
    }
}